// Round 1
// baseline (4500.282 us; speedup 1.0000x reference)
//
#include <hip/hip_runtime.h>
#include <math.h>

namespace {

constexpr int NB  = 64;     // batch
constexpr int NL  = 196;    // L (enc positions)
constexpr int NE  = 2048;   // E
constexpr int ND  = 512;    // D
constexpr int NA  = 512;    // A (attention dim)
constexpr int NM  = 512;    // M (embed dim)
constexpr int NV  = 30000;  // vocab
constexpr int NT  = 21;     // T
constexpr int NML = 20;     // max_len
constexpr int NSPLIT = 8;   // gates GEMM K-split
constexpr int KSL = (NM + NE + ND) / NSPLIT;  // 3072/8 = 384

// workspace layout (float offsets)
constexpr size_t WS_MEAN  = 0;
constexpr size_t WS_H     = WS_MEAN  + (size_t)NB * NE;
constexpr size_t WS_C     = WS_H     + (size_t)NB * ND;
constexpr size_t WS_EPROJ = WS_C     + (size_t)NB * ND;
constexpr size_t WS_ALPHA = WS_EPROJ + (size_t)NB * NL * NA;
constexpr size_t WS_GCTX  = WS_ALPHA + (size_t)NB * NL;
constexpr size_t WS_P     = WS_GCTX  + (size_t)NB * NE;

__device__ __forceinline__ float sigmoidf_(float x) { return 1.f / (1.f + expf(-x)); }

// mean over L: mean_enc[b,e] = (1/L) sum_l enc[b,l,e]
__global__ void k_mean(const float* __restrict__ enc, float* __restrict__ mean_enc) {
  int idx = blockIdx.x * 256 + threadIdx.x;        // b*2048 + e
  int b = idx >> 11, e = idx & (NE - 1);
  const float* p = enc + (size_t)b * NL * NE + e;
  float s = 0.f;
  for (int l = 0; l < NL; ++l) s += p[(size_t)l * NE];
  mean_enc[idx] = s * (1.f / NL);
}

// h0/c0 = tanh(mean_enc @ W + b)
__global__ void k_init(const float* __restrict__ mean_enc,
                       const float* __restrict__ W_h0, const float* __restrict__ b_h0,
                       const float* __restrict__ W_c0, const float* __restrict__ b_c0,
                       float* __restrict__ h, float* __restrict__ c) {
  int idx = blockIdx.x * 256 + threadIdx.x;        // b*512 + j
  int b = idx >> 9, j = idx & (ND - 1);
  float ah = b_h0[j], ac = b_c0[j];
  const float* mp = mean_enc + (size_t)b * NE;
  for (int k = 0; k < NE; ++k) {
    float m = mp[k];
    ah = fmaf(m, W_h0[(size_t)k * ND + j], ah);
    ac = fmaf(m, W_c0[(size_t)k * ND + j], ac);
  }
  h[idx] = tanhf(ah);
  c[idx] = tanhf(ac);
}

// C[m,n] = bias[n] + sum_k A[m,k]*B[k,n]; M%64==0, N%64==0, K%16==0
__global__ void k_gemm64(const float* __restrict__ Amat, const float* __restrict__ Bmat,
                         const float* __restrict__ bias, float* __restrict__ C,
                         int Mdim, int Ndim, int Kdim) {
  __shared__ __align__(16) float As[16][68];   // [k][m], 272B rows -> 16B aligned
  __shared__ __align__(16) float Bs[16][68];   // [k][n]
  int bm = blockIdx.x * 64, bn = blockIdx.y * 64;
  int tid = threadIdx.x;
  int tx = tid & 15, ty = tid >> 4;
  float acc[4][4] = {};
  for (int k0 = 0; k0 < Kdim; k0 += 16) {
#pragma unroll
    for (int i = 0; i < 4; ++i) {
      int cc = tid & 15, r = (tid >> 4) + i * 16;
      As[cc][r] = Amat[(size_t)(bm + r) * Kdim + k0 + cc];
    }
#pragma unroll
    for (int i = 0; i < 4; ++i) {
      int idx = tid + i * 256; int r = idx >> 6, cn = idx & 63;
      Bs[r][cn] = Bmat[(size_t)(k0 + r) * Ndim + bn + cn];
    }
    __syncthreads();
#pragma unroll
    for (int kk = 0; kk < 16; ++kk) {
      float4 av = *(const float4*)&As[kk][ty * 4];
      float4 bv = *(const float4*)&Bs[kk][tx * 4];
      float a_[4] = {av.x, av.y, av.z, av.w};
      float b_[4] = {bv.x, bv.y, bv.z, bv.w};
#pragma unroll
      for (int i = 0; i < 4; ++i)
#pragma unroll
        for (int j = 0; j < 4; ++j) acc[i][j] = fmaf(a_[i], b_[j], acc[i][j]);
    }
    __syncthreads();
  }
  for (int i = 0; i < 4; ++i) {
    int m = bm + ty * 4 + i;
    for (int j = 0; j < 4; ++j) {
      int n = bn + tx * 4 + j;
      C[(size_t)m * Ndim + n] = acc[i][j] + bias[n];
    }
  }
}

// per-step fused: d = h@W_dec+b_dec (LDS), energy per l (wave), softmax, alpha out
__global__ void k_att(const float* __restrict__ h, const float* __restrict__ W_dec,
                      const float* __restrict__ b_dec, const float* __restrict__ e_proj,
                      const float* __restrict__ w_att, const float* __restrict__ b_att,
                      const int* __restrict__ clen, float* __restrict__ alpha,
                      float* __restrict__ alphas_out, int t) {
  int b = blockIdx.x;
  int tid = threadIdx.x;                 // block = 512
  __shared__ float d_sh[NA];
  __shared__ float e_sh[NL];
  __shared__ float red[16];
  {
    float acc = b_dec[tid];
    const float* hp = h + (size_t)b * ND;
    for (int k = 0; k < ND; ++k) acc = fmaf(hp[k], W_dec[(size_t)k * NA + tid], acc);
    d_sh[tid] = acc;
  }
  __syncthreads();
  int wv = tid >> 6, lane = tid & 63;
  for (int l = wv; l < NL; l += 8) {
    const float* ep = e_proj + (size_t)(b * NL + l) * NA;
    float acc = 0.f;
#pragma unroll
    for (int i = 0; i < 8; ++i) {
      int a = lane + i * 64;
      float v = ep[a] + d_sh[a];
      acc = fmaf(fmaxf(v, 0.f), w_att[a], acc);
    }
#pragma unroll
    for (int off = 32; off; off >>= 1) acc += __shfl_down(acc, off);
    if (lane == 0) e_sh[l] = acc + b_att[0];
  }
  __syncthreads();
  float v = (tid < NL) ? e_sh[tid] : -INFINITY;
  float mx = v;
#pragma unroll
  for (int off = 32; off; off >>= 1) mx = fmaxf(mx, __shfl_down(mx, off));
  if (lane == 0) red[wv] = mx;
  __syncthreads();
  if (tid == 0) { float m2 = red[0]; for (int i = 1; i < 8; ++i) m2 = fmaxf(m2, red[i]); red[0] = m2; }
  __syncthreads();
  mx = red[0];
  float ex = (tid < NL) ? expf(v - mx) : 0.f;
  float sm = ex;
#pragma unroll
  for (int off = 32; off; off >>= 1) sm += __shfl_down(sm, off);
  if (lane == 0) red[8 + wv] = sm;
  __syncthreads();
  if (tid == 0) { float s2 = 0.f; for (int i = 0; i < 8; ++i) s2 += red[8 + i]; red[0] = 1.f / s2; }
  __syncthreads();
  float inv = red[0];
  if (tid < NL) {
    float al = ex * inv;
    alpha[(size_t)b * NL + tid] = al;
    float mf = ((clen[b] - 1) > t) ? 1.f : 0.f;
    alphas_out[((size_t)b * NML + t) * NL + tid] = al * mf;
  }
}

// per-step fused: ctx[b,e] = sum_l alpha*enc ; gate = sigmoid(h@W_beta+b_beta); gctx = gate*ctx
// 4 batches per thread (cuts W_beta re-reads 4x). grid (E/256, B/4)
__global__ void k_ctxgate(const float* __restrict__ enc, const float* __restrict__ alpha,
                          const float* __restrict__ h, const float* __restrict__ W_beta,
                          const float* __restrict__ b_beta, float* __restrict__ gctx) {
  int e = blockIdx.x * 256 + threadIdx.x;
  int b0 = blockIdx.y * 4;
  __shared__ float al[4][NL];
  for (int i = threadIdx.x; i < 4 * NL; i += 256)
    al[i / NL][i % NL] = alpha[(size_t)(b0 + i / NL) * NL + (i % NL)];
  __syncthreads();
  float cx[4] = {0.f, 0.f, 0.f, 0.f};
  const float* p = enc + (size_t)b0 * NL * NE + e;
  for (int l = 0; l < NL; ++l) {
#pragma unroll
    for (int q = 0; q < 4; ++q) cx[q] = fmaf(al[q][l], p[(size_t)(q * NL + l) * NE], cx[q]);
  }
  float b0v = b_beta[e];
  float g[4] = {b0v, b0v, b0v, b0v};
  for (int k = 0; k < ND; ++k) {
    float w = W_beta[(size_t)k * NE + e];
#pragma unroll
    for (int q = 0; q < 4; ++q) g[q] = fmaf(h[(size_t)(b0 + q) * ND + k], w, g[q]);
  }
#pragma unroll
  for (int q = 0; q < 4; ++q) gctx[(size_t)(b0 + q) * NE + e] = cx[q] * sigmoidf_(g[q]);
}

// gates partial GEMM: x=[emb_t | gctx | h] (K=3072) @ [W_ih;W_hh] -> P[ks][b][4D]
// grid (2048/64, NSPLIT), block 256, 64x64 tile, 4x4 per thread
__global__ void k_gates(const float* __restrict__ emb, const int* __restrict__ caps, int t,
                        const float* __restrict__ gctx, const float* __restrict__ h,
                        const float* __restrict__ W_ih, const float* __restrict__ W_hh,
                        float* __restrict__ P) {
  int jb = blockIdx.x * 64;
  int ks = blockIdx.y;
  int tid = threadIdx.x, tx = tid & 15, ty = tid >> 4;
  __shared__ __align__(16) float Xs[16][68];   // [k][b]
  __shared__ __align__(16) float Ws[16][64];   // [k][j]
  float acc[4][4] = {};
  int kbase = ks * KSL;
  for (int kt = 0; kt < KSL; kt += 16) {
    int k0 = kbase + kt;
#pragma unroll
    for (int i = 0; i < 4; ++i) {
      int kk = tid & 15, bb = (tid >> 4) + i * 16;
      int k = k0 + kk;
      float x;
      if (k < NM)              x = emb[(size_t)caps[bb * NT + t] * NM + k];
      else if (k < NM + NE)    x = gctx[(size_t)bb * NE + (k - NM)];
      else                     x = h[(size_t)bb * ND + (k - NM - NE)];
      Xs[kk][bb] = x;
    }
#pragma unroll
    for (int i = 0; i < 4; ++i) {
      int idx = tid + i * 256; int kk = idx >> 6, jj = idx & 63;
      int k = k0 + kk;
      float w = (k < NM + NE) ? W_ih[(size_t)k * (4 * ND) + jb + jj]
                              : W_hh[(size_t)(k - NM - NE) * (4 * ND) + jb + jj];
      Ws[kk][jj] = w;
    }
    __syncthreads();
#pragma unroll
    for (int kk = 0; kk < 16; ++kk) {
      float4 av = *(const float4*)&Xs[kk][ty * 4];
      float4 bv = *(const float4*)&Ws[kk][tx * 4];
      float a_[4] = {av.x, av.y, av.z, av.w};
      float b_[4] = {bv.x, bv.y, bv.z, bv.w};
#pragma unroll
      for (int i = 0; i < 4; ++i)
#pragma unroll
        for (int j = 0; j < 4; ++j) acc[i][j] = fmaf(a_[i], b_[j], acc[i][j]);
    }
    __syncthreads();
  }
#pragma unroll
  for (int i = 0; i < 4; ++i) {
    int bb = ty * 4 + i;
#pragma unroll
    for (int j = 0; j < 4; ++j)
      P[((size_t)ks * NB + bb) * (4 * ND) + jb + tx * 4 + j] = acc[i][j];
  }
}

// reduce K-split partials + biases, LSTM pointwise, update h/c in place
__global__ void k_lstm(const float* __restrict__ P, const float* __restrict__ b_ih,
                       const float* __restrict__ b_hh, float* __restrict__ h,
                       float* __restrict__ c) {
  int idx = blockIdx.x * 256 + threadIdx.x;   // b*512 + j
  int b = idx >> 9, j = idx & (ND - 1);
  float gi = b_ih[j] + b_hh[j];
  float gf = b_ih[j + ND] + b_hh[j + ND];
  float gg = b_ih[j + 2 * ND] + b_hh[j + 2 * ND];
  float go = b_ih[j + 3 * ND] + b_hh[j + 3 * ND];
  for (int s = 0; s < NSPLIT; ++s) {
    const float* Pp = P + ((size_t)s * NB + b) * (4 * ND);
    gi += Pp[j]; gf += Pp[j + ND]; gg += Pp[j + 2 * ND]; go += Pp[j + 3 * ND];
  }
  float cn = sigmoidf_(gf) * c[idx] + sigmoidf_(gi) * tanhf(gg);
  float hn = sigmoidf_(go) * tanhf(cn);
  c[idx] = cn;
  h[idx] = hn;
}

// pred = mask * (h @ W_fc + b_fc); grid ceil(V/64), 64x64 tile, 4x4 per thread
__global__ void k_pred(const float* __restrict__ h, const float* __restrict__ W_fc,
                       const float* __restrict__ b_fc, const int* __restrict__ clen,
                       float* __restrict__ preds, int t) {
  int vb = blockIdx.x * 64;
  int tid = threadIdx.x, tx = tid & 15, ty = tid >> 4;
  __shared__ __align__(16) float Hs[32][68];   // [k][b]
  __shared__ __align__(16) float Ws[32][64];   // [k][v]
  float acc[4][4] = {};
  for (int k0 = 0; k0 < ND; k0 += 32) {
#pragma unroll
    for (int i = 0; i < 8; ++i) {
      int kk = tid & 31, bb = (tid >> 5) + i * 8;
      Hs[kk][bb] = h[(size_t)bb * ND + k0 + kk];
    }
#pragma unroll
    for (int i = 0; i < 8; ++i) {
      int idx = tid + i * 256; int kk = idx >> 6, vv = idx & 63;
      int v = vb + vv;
      Ws[kk][vv] = (v < NV) ? W_fc[(size_t)(k0 + kk) * NV + v] : 0.f;
    }
    __syncthreads();
#pragma unroll
    for (int kk = 0; kk < 32; ++kk) {
      float4 av = *(const float4*)&Hs[kk][ty * 4];
      float4 bv = *(const float4*)&Ws[kk][tx * 4];
      float a_[4] = {av.x, av.y, av.z, av.w};
      float b_[4] = {bv.x, bv.y, bv.z, bv.w};
#pragma unroll
      for (int i = 0; i < 4; ++i)
#pragma unroll
        for (int j = 0; j < 4; ++j) acc[i][j] = fmaf(a_[i], b_[j], acc[i][j]);
    }
    __syncthreads();
  }
#pragma unroll
  for (int i = 0; i < 4; ++i) {
    int bb = ty * 4 + i;
    float mf = ((clen[bb] - 1) > t) ? 1.f : 0.f;
#pragma unroll
    for (int j = 0; j < 4; ++j) {
      int v = vb + tx * 4 + j;
      if (v < NV) preds[((size_t)bb * NML + t) * NV + v] = mf * (acc[i][j] + b_fc[v]);
    }
  }
}

}  // namespace

extern "C" void kernel_launch(void* const* d_in, const int* in_sizes, int n_in,
                              void* d_out, int out_size, void* d_ws, size_t ws_size,
                              hipStream_t stream) {
  (void)in_sizes; (void)n_in; (void)out_size; (void)ws_size;
  const float* enc    = (const float*)d_in[0];
  const int*   caps   = (const int*)d_in[1];
  const int*   clen   = (const int*)d_in[2];
  const float* W_enc  = (const float*)d_in[3];
  const float* b_enc  = (const float*)d_in[4];
  const float* W_dec  = (const float*)d_in[5];
  const float* b_dec  = (const float*)d_in[6];
  const float* w_att  = (const float*)d_in[7];
  const float* b_att  = (const float*)d_in[8];
  const float* emb    = (const float*)d_in[9];
  const float* W_ih   = (const float*)d_in[10];
  const float* b_ih   = (const float*)d_in[11];
  const float* W_hh   = (const float*)d_in[12];
  const float* b_hh   = (const float*)d_in[13];
  const float* W_h0   = (const float*)d_in[14];
  const float* b_h0   = (const float*)d_in[15];
  const float* W_c0   = (const float*)d_in[16];
  const float* b_c0   = (const float*)d_in[17];
  const float* W_beta = (const float*)d_in[18];
  const float* b_beta = (const float*)d_in[19];
  const float* W_fc   = (const float*)d_in[20];
  const float* b_fc   = (const float*)d_in[21];

  float* ws      = (float*)d_ws;
  float* preds   = (float*)d_out;                          // [B][ML][V]
  float* alphas  = preds + (size_t)NB * NML * NV;          // [B][ML][L]

  float* mean_enc = ws + WS_MEAN;
  float* h        = ws + WS_H;
  float* c        = ws + WS_C;
  float* e_proj   = ws + WS_EPROJ;
  float* alpha    = ws + WS_ALPHA;
  float* gctx     = ws + WS_GCTX;
  float* P        = ws + WS_P;

  k_mean<<<(NB * NE) / 256, 256, 0, stream>>>(enc, mean_enc);
  k_init<<<(NB * ND) / 256, 256, 0, stream>>>(mean_enc, W_h0, b_h0, W_c0, b_c0, h, c);
  k_gemm64<<<dim3((NB * NL) / 64, NA / 64), 256, 0, stream>>>(enc, W_enc, b_enc, e_proj,
                                                              NB * NL, NA, NE);
  for (int t = 0; t < NML; ++t) {
    k_att<<<NB, 512, 0, stream>>>(h, W_dec, b_dec, e_proj, w_att, b_att, clen, alpha, alphas, t);
    k_ctxgate<<<dim3(NE / 256, NB / 4), 256, 0, stream>>>(enc, alpha, h, W_beta, b_beta, gctx);
    k_gates<<<dim3((4 * ND) / 64, NSPLIT), 256, 0, stream>>>(emb, caps, t, gctx, h, W_ih, W_hh, P);
    k_lstm<<<(NB * ND) / 256, 256, 0, stream>>>(P, b_ih, b_hh, h, c);
    k_pred<<<(NV + 63) / 64, 256, 0, stream>>>(h, W_fc, b_fc, clen, preds, t);
  }
}

// Round 2
// 3091.307 us; speedup vs baseline: 1.4558x; 1.4558x over previous
//
#include <hip/hip_runtime.h>
#include <math.h>

namespace {

constexpr int NB  = 64;     // batch
constexpr int NL  = 196;    // L
constexpr int NE  = 2048;   // E
constexpr int ND  = 512;    // D
constexpr int NA  = 512;    // A
constexpr int NM  = 512;    // M
constexpr int NV  = 30000;  // vocab
constexpr int NT  = 21;     // T
constexpr int NML = 20;     // max_len
constexpr int KX  = NM + NE + ND;   // 3072 x_cat K
constexpr int NG  = 4 * ND;         // 2048 gates out
constexpr int KSPL = 4;             // gates K-split
constexpr int KSL  = KX / KSPL;     // 768

// workspace layout (float offsets, all multiples of 4 for 16B alignment)
constexpr size_t WS_MEAN = 0;                               // [64][2048] f32
constexpr size_t WS_H    = WS_MEAN + (size_t)NB * NE;       // [64][512] f32
constexpr size_t WS_C    = WS_H    + (size_t)NB * ND;       // [64][512] f32
constexpr size_t WS_ALPH = WS_C    + (size_t)NB * ND;       // [64][196] f32
constexpr size_t WS_P    = WS_ALPH + (size_t)NB * NL;       // [4][64][2048] f32
constexpr size_t WS_HBF  = WS_P    + (size_t)KSPL * NB * NG;        // [64][512] bf16
constexpr size_t WS_XCAT = WS_HBF  + (size_t)NB * ND / 2;           // [64][3072] bf16
constexpr size_t WS_EPB  = WS_XCAT + (size_t)NB * KX / 2;           // [12544][512] bf16
constexpr size_t WS_WET  = WS_EPB  + (size_t)NB * NL * NA / 2;      // [512][2048] bf16
constexpr size_t WS_WIHT = WS_WET  + (size_t)NA * NE / 2;           // [2048][3072] bf16
constexpr size_t WS_WFCT = WS_WIHT + (size_t)NG * KX / 2;           // [30000][512] bf16

typedef __attribute__((ext_vector_type(8))) short short8v;
typedef __attribute__((ext_vector_type(4))) float f32x4;

__device__ __forceinline__ float sigmoidf_(float x) { return 1.f / (1.f + expf(-x)); }
__device__ __forceinline__ short f2bf(float f) {
  unsigned u = __float_as_uint(f);
  return (short)((u + 0x7FFFu + ((u >> 16) & 1u)) >> 16);
}
__device__ __forceinline__ float bf2f(short s) {
  return __uint_as_float(((unsigned)(unsigned short)s) << 16);
}

// ---------- MFMA GEMM building blocks (A [M][K] bf16-ish, B [N][K] bf16) ----------
// LDS tile layout: [row][64 k] bf16, 8 chunks of 16B per row, chunk slot = kblk ^ (row&7)
// -> ds_read_b128 fragment reads hit each bank-quad exactly 2x (free, m136).

template <int R>  // stage R rows x 64 k of bf16 from row-major src (already offset to (row0,k0))
__device__ __forceinline__ void stage_bf16(const short* __restrict__ src, int ldK,
                                           int rowClamp, short* lds, int tid) {
#pragma unroll
  for (int c = tid; c < R * 8; c += 256) {
    int row = c >> 3, kb = c & 7;
    int r = row < rowClamp ? row : rowClamp;
    int4 v = *(const int4*)(src + (size_t)r * ldK + kb * 8);
    *(int4*)(lds + row * 64 + ((kb ^ (row & 7)) << 3)) = v;
  }
}

template <int R>  // stage R rows x 64 k, converting f32 -> bf16 on the fly
__device__ __forceinline__ void stage_f32cvt(const float* __restrict__ src, int ldK,
                                             short* lds, int tid) {
#pragma unroll
  for (int c = tid; c < R * 8; c += 256) {
    int row = c >> 3, kb = c & 7;
    const float* p = src + (size_t)row * ldK + kb * 8;
    float4 x = *(const float4*)p;
    float4 y = *(const float4*)(p + 4);
    short8v s;
    s[0] = f2bf(x.x); s[1] = f2bf(x.y); s[2] = f2bf(x.z); s[3] = f2bf(x.w);
    s[4] = f2bf(y.x); s[5] = f2bf(y.y); s[6] = f2bf(y.z); s[7] = f2bf(y.w);
    *(short8v*)(lds + row * 64 + ((kb ^ (row & 7)) << 3)) = s;
  }
}

template <int FM, int FN>  // one BK=64 step: 2 x (FM x FN) mfma_16x16x32
__device__ __forceinline__ void mma_tiles(const short* ldsA, const short* ldsB,
                                          int wr, int wc, int lane, f32x4 acc[FM][FN]) {
  int l15 = lane & 15;
#pragma unroll
  for (int kk = 0; kk < 2; ++kk) {
    int kb0 = kk * 4 + (lane >> 4);
    short8v a[FM], b[FN];
#pragma unroll
    for (int m = 0; m < FM; ++m) {
      int row = wr * FM * 16 + m * 16 + l15;
      a[m] = *(const short8v*)(ldsA + row * 64 + ((kb0 ^ (row & 7)) << 3));
    }
#pragma unroll
    for (int n = 0; n < FN; ++n) {
      int row = wc * FN * 16 + n * 16 + l15;
      b[n] = *(const short8v*)(ldsB + row * 64 + ((kb0 ^ (row & 7)) << 3));
    }
#pragma unroll
    for (int m = 0; m < FM; ++m)
#pragma unroll
      for (int n = 0; n < FN; ++n)
        acc[m][n] = __builtin_amdgcn_mfma_f32_16x16x32_bf16(a[m], b[n], acc[m][n], 0, 0, 0);
  }
}

// ---------- one-time conversions ----------

// transpose+convert: dst[n][kOff+k] = bf16(src[k][n]); src [Ks][Ns] f32
__global__ __launch_bounds__(256) void k_tcvt(const float* __restrict__ src, int Ks, int Ns,
                                              short* __restrict__ dst, int ldDst, int kOff) {
  __shared__ float t[32][33];
  int n0 = blockIdx.x * 32, k0 = blockIdx.y * 32;
  int tx = threadIdx.x, ty = threadIdx.y;  // 32 x 8
#pragma unroll
  for (int i = 0; i < 32; i += 8) {
    int k = k0 + ty + i, n = n0 + tx;
    t[ty + i][tx] = (k < Ks && n < Ns) ? src[(size_t)k * Ns + n] : 0.f;
  }
  __syncthreads();
#pragma unroll
  for (int i = 0; i < 32; i += 8) {
    int n = n0 + ty + i, k = k0 + tx;
    if (n < Ns && k < Ks) dst[(size_t)n * ldDst + kOff + k] = f2bf(t[tx][ty + i]);
  }
}

// ---------- prologue ----------

__global__ void k_mean(const float* __restrict__ enc, float* __restrict__ mean_enc) {
  int idx = blockIdx.x * 256 + threadIdx.x;  // b*2048 + e
  int b = idx >> 11, e = idx & (NE - 1);
  const float* p = enc + (size_t)b * NL * NE + e;
  float s = 0.f;
  for (int l = 0; l < NL; ++l) s += p[(size_t)l * NE];
  mean_enc[idx] = s * (1.f / NL);
}

__global__ void k_init(const float* __restrict__ mean_enc,
                       const float* __restrict__ W_h0, const float* __restrict__ b_h0,
                       const float* __restrict__ W_c0, const float* __restrict__ b_c0,
                       float* __restrict__ h, float* __restrict__ c,
                       short* __restrict__ h_bf, short* __restrict__ xcat) {
  int idx = blockIdx.x * 256 + threadIdx.x;  // b*512 + j
  int b = idx >> 9, j = idx & (ND - 1);
  float ah = b_h0[j], ac = b_c0[j];
  const float* mp = mean_enc + (size_t)b * NE;
  for (int k = 0; k < NE; ++k) {
    float m = mp[k];
    ah = fmaf(m, W_h0[(size_t)k * ND + j], ah);
    ac = fmaf(m, W_c0[(size_t)k * ND + j], ac);
  }
  float hv = tanhf(ah);
  h[idx] = hv;
  c[idx] = tanhf(ac);
  short hb = f2bf(hv);
  h_bf[idx] = hb;
  xcat[(size_t)b * KX + NM + NE + j] = hb;
}

// e_proj = enc @ W_enc + b_enc, stored bf16. grid (98, 8), 256 thr
__global__ __launch_bounds__(256) void k_eproj(const float* __restrict__ enc,
                                               const short* __restrict__ We_t,
                                               const float* __restrict__ b_enc,
                                               short* __restrict__ e_proj) {
  constexpr int FM = 4, FN = 2;  // 128 x 64 tile
  __shared__ short ldsA[128 * 64], ldsB[64 * 64];
  int bm = blockIdx.x * 128, bn = blockIdx.y * 64;
  int tid = threadIdx.x, lane = tid & 63, wave = tid >> 6, wr = wave >> 1, wc = wave & 1;
  f32x4 acc[FM][FN];
#pragma unroll
  for (int m = 0; m < FM; ++m)
#pragma unroll
    for (int n = 0; n < FN; ++n) acc[m][n] = (f32x4){0.f, 0.f, 0.f, 0.f};
  for (int k0 = 0; k0 < NE; k0 += 64) {
    __syncthreads();
    stage_f32cvt<128>(enc + (size_t)bm * NE + k0, NE, ldsA, tid);
    stage_bf16<64>(We_t + (size_t)bn * NE + k0, NE, 63, ldsB, tid);
    __syncthreads();
    mma_tiles<FM, FN>(ldsA, ldsB, wr, wc, lane, acc);
  }
#pragma unroll
  for (int m = 0; m < FM; ++m)
#pragma unroll
    for (int n = 0; n < FN; ++n) {
      int col = bn + wc * FN * 16 + n * 16 + (lane & 15);
      float bias = b_enc[col];
#pragma unroll
      for (int r = 0; r < 4; ++r) {
        int row = bm + wr * FM * 16 + m * 16 + (lane >> 4) * 4 + r;
        e_proj[(size_t)row * NA + col] = f2bf(acc[m][n][r] + bias);
      }
    }
}

// ---------- per-step kernels ----------

// attention: d = h@W_dec+b_dec, energy, softmax; writes alpha, masked alphas, x_cat emb slice
__global__ __launch_bounds__(512) void k_att(const float* __restrict__ h,
                                             const float* __restrict__ W_dec,
                                             const float* __restrict__ b_dec,
                                             const short* __restrict__ e_proj,
                                             const float* __restrict__ w_att,
                                             const float* __restrict__ b_att,
                                             const int* __restrict__ clen,
                                             const int* __restrict__ caps,
                                             const float* __restrict__ emb,
                                             float* __restrict__ alpha,
                                             float* __restrict__ alphas_out,
                                             short* __restrict__ xcat, int t) {
  int b = blockIdx.x;
  int tid = threadIdx.x;  // 512
  __shared__ float d_sh[NA];
  __shared__ float e_sh[NL];
  __shared__ float red[16];
  {  // x_cat emb slice for this step
    int cap = caps[b * NT + t];
    xcat[(size_t)b * KX + tid] = f2bf(emb[(size_t)cap * NM + tid]);
  }
  {
    float acc = b_dec[tid];
    const float* hp = h + (size_t)b * ND;
    for (int k = 0; k < ND; ++k) acc = fmaf(hp[k], W_dec[(size_t)k * NA + tid], acc);
    d_sh[tid] = acc;
  }
  __syncthreads();
  int wv = tid >> 6, lane = tid & 63;
  for (int l = wv; l < NL; l += 8) {
    const short* ep = e_proj + (size_t)(b * NL + l) * NA;
    float acc = 0.f;
#pragma unroll
    for (int i = 0; i < 8; ++i) {
      int a = lane + i * 64;
      float v = bf2f(ep[a]) + d_sh[a];
      acc = fmaf(fmaxf(v, 0.f), w_att[a], acc);
    }
#pragma unroll
    for (int off = 32; off; off >>= 1) acc += __shfl_down(acc, off);
    if (lane == 0) e_sh[l] = acc + b_att[0];
  }
  __syncthreads();
  float v = (tid < NL) ? e_sh[tid] : -INFINITY;
  float mx = v;
#pragma unroll
  for (int off = 32; off; off >>= 1) mx = fmaxf(mx, __shfl_down(mx, off));
  if (lane == 0) red[wv] = mx;
  __syncthreads();
  if (tid == 0) { float m2 = red[0]; for (int i = 1; i < 8; ++i) m2 = fmaxf(m2, red[i]); red[0] = m2; }
  __syncthreads();
  mx = red[0];
  float ex = (tid < NL) ? expf(v - mx) : 0.f;
  float sm = ex;
#pragma unroll
  for (int off = 32; off; off >>= 1) sm += __shfl_down(sm, off);
  if (lane == 0) red[8 + wv] = sm;
  __syncthreads();
  if (tid == 0) { float s2 = 0.f; for (int i = 0; i < 8; ++i) s2 += red[8 + i]; red[0] = 1.f / s2; }
  __syncthreads();
  float inv = red[0];
  if (tid < NL) {
    float al = ex * inv;
    alpha[(size_t)b * NL + tid] = al;
    float mf = ((clen[b] - 1) > t) ? 1.f : 0.f;
    alphas_out[((size_t)b * NML + t) * NL + tid] = al * mf;
  }
}

// ctx + gate, writes bf16 gated-ctx into x_cat. grid (E/256, B/4)
__global__ __launch_bounds__(256) void k_ctxgate(const float* __restrict__ enc,
                                                 const float* __restrict__ alpha,
                                                 const float* __restrict__ h,
                                                 const float* __restrict__ W_beta,
                                                 const float* __restrict__ b_beta,
                                                 short* __restrict__ xcat) {
  int e = blockIdx.x * 256 + threadIdx.x;
  int b0 = blockIdx.y * 4;
  __shared__ float al[4][NL];
  for (int i = threadIdx.x; i < 4 * NL; i += 256)
    al[i / NL][i % NL] = alpha[(size_t)(b0 + i / NL) * NL + (i % NL)];
  __syncthreads();
  float cx[4] = {0.f, 0.f, 0.f, 0.f};
  const float* p = enc + (size_t)b0 * NL * NE + e;
  for (int l = 0; l < NL; ++l) {
#pragma unroll
    for (int q = 0; q < 4; ++q) cx[q] = fmaf(al[q][l], p[(size_t)(q * NL + l) * NE], cx[q]);
  }
  float b0v = b_beta[e];
  float g[4] = {b0v, b0v, b0v, b0v};
  for (int k = 0; k < ND; ++k) {
    float w = W_beta[(size_t)k * NE + e];
#pragma unroll
    for (int q = 0; q < 4; ++q) g[q] = fmaf(h[(size_t)(b0 + q) * ND + k], w, g[q]);
  }
#pragma unroll
  for (int q = 0; q < 4; ++q)
    xcat[(size_t)(b0 + q) * KX + NM + e] = f2bf(cx[q] * sigmoidf_(g[q]));
}

// gates partial GEMM: x_cat [64][3072] @ Wihh_t^T -> P[ks][64][2048]. grid (16, 4)
__global__ __launch_bounds__(256) void k_gates(const short* __restrict__ xcat,
                                               const short* __restrict__ Wihh_t,
                                               float* __restrict__ P) {
  constexpr int FM = 2, FN = 4;  // 64 x 128 tile
  __shared__ short ldsA[64 * 64], ldsB[128 * 64];
  int bn = blockIdx.x * 128, ks = blockIdx.y;
  int tid = threadIdx.x, lane = tid & 63, wave = tid >> 6, wr = wave >> 1, wc = wave & 1;
  f32x4 acc[FM][FN];
#pragma unroll
  for (int m = 0; m < FM; ++m)
#pragma unroll
    for (int n = 0; n < FN; ++n) acc[m][n] = (f32x4){0.f, 0.f, 0.f, 0.f};
  int kend = (ks + 1) * KSL;
  for (int k0 = ks * KSL; k0 < kend; k0 += 64) {
    __syncthreads();
    stage_bf16<64>(xcat + k0, KX, 63, ldsA, tid);
    stage_bf16<128>(Wihh_t + (size_t)bn * KX + k0, KX, 127, ldsB, tid);
    __syncthreads();
    mma_tiles<FM, FN>(ldsA, ldsB, wr, wc, lane, acc);
  }
#pragma unroll
  for (int m = 0; m < FM; ++m)
#pragma unroll
    for (int n = 0; n < FN; ++n) {
      int col = bn + wc * FN * 16 + n * 16 + (lane & 15);
#pragma unroll
      for (int r = 0; r < 4; ++r) {
        int row = wr * FM * 16 + m * 16 + (lane >> 4) * 4 + r;
        P[((size_t)ks * NB + row) * NG + col] = acc[m][n][r];
      }
    }
}

// reduce K-split partials + biases, LSTM pointwise, update h/c, emit bf16 h
__global__ void k_lstm(const float* __restrict__ P, const float* __restrict__ b_ih,
                       const float* __restrict__ b_hh, float* __restrict__ h,
                       float* __restrict__ c, short* __restrict__ h_bf,
                       short* __restrict__ xcat) {
  int idx = blockIdx.x * 256 + threadIdx.x;  // b*512 + j
  int b = idx >> 9, j = idx & (ND - 1);
  float gi = b_ih[j] + b_hh[j];
  float gf = b_ih[j + ND] + b_hh[j + ND];
  float gg = b_ih[j + 2 * ND] + b_hh[j + 2 * ND];
  float go = b_ih[j + 3 * ND] + b_hh[j + 3 * ND];
  for (int s = 0; s < KSPL; ++s) {
    const float* Pp = P + ((size_t)s * NB + b) * NG;
    gi += Pp[j]; gf += Pp[j + ND]; gg += Pp[j + 2 * ND]; go += Pp[j + 3 * ND];
  }
  float cn = sigmoidf_(gf) * c[idx] + sigmoidf_(gi) * tanhf(gg);
  float hn = sigmoidf_(go) * tanhf(cn);
  c[idx] = cn;
  h[idx] = hn;
  short hb = f2bf(hn);
  h_bf[idx] = hb;
  xcat[(size_t)b * KX + NM + NE + j] = hb;
}

// pred = mask * (h_bf @ Wfc_t^T + b_fc). grid (235)
__global__ __launch_bounds__(256) void k_pred(const short* __restrict__ h_bf,
                                              const short* __restrict__ Wfc_t,
                                              const float* __restrict__ b_fc,
                                              const int* __restrict__ clen,
                                              float* __restrict__ preds, int t) {
  constexpr int FM = 2, FN = 4;  // 64 x 128 tile
  __shared__ short ldsA[64 * 64], ldsB[128 * 64];
  int bn = blockIdx.x * 128;
  int tid = threadIdx.x, lane = tid & 63, wave = tid >> 6, wr = wave >> 1, wc = wave & 1;
  int rowClampB = (NV - 1) - bn;  // clamp OOB vocab rows; results masked at store
  f32x4 acc[FM][FN];
#pragma unroll
  for (int m = 0; m < FM; ++m)
#pragma unroll
    for (int n = 0; n < FN; ++n) acc[m][n] = (f32x4){0.f, 0.f, 0.f, 0.f};
  for (int k0 = 0; k0 < ND; k0 += 64) {
    __syncthreads();
    stage_bf16<64>(h_bf + k0, ND, 63, ldsA, tid);
    stage_bf16<128>(Wfc_t + (size_t)bn * ND + k0, ND, rowClampB, ldsB, tid);
    __syncthreads();
    mma_tiles<FM, FN>(ldsA, ldsB, wr, wc, lane, acc);
  }
#pragma unroll
  for (int m = 0; m < FM; ++m)
#pragma unroll
    for (int n = 0; n < FN; ++n) {
      int col = bn + wc * FN * 16 + n * 16 + (lane & 15);
      if (col < NV) {
        float bias = b_fc[col];
#pragma unroll
        for (int r = 0; r < 4; ++r) {
          int row = wr * FM * 16 + m * 16 + (lane >> 4) * 4 + r;  // = batch b
          float mf = ((clen[row] - 1) > t) ? 1.f : 0.f;
          preds[((size_t)row * NML + t) * NV + col] = mf * (acc[m][n][r] + bias);
        }
      }
    }
}

}  // namespace

extern "C" void kernel_launch(void* const* d_in, const int* in_sizes, int n_in,
                              void* d_out, int out_size, void* d_ws, size_t ws_size,
                              hipStream_t stream) {
  (void)in_sizes; (void)n_in; (void)out_size; (void)ws_size;
  const float* enc    = (const float*)d_in[0];
  const int*   caps   = (const int*)d_in[1];
  const int*   clen   = (const int*)d_in[2];
  const float* W_enc  = (const float*)d_in[3];
  const float* b_enc  = (const float*)d_in[4];
  const float* W_dec  = (const float*)d_in[5];
  const float* b_dec  = (const float*)d_in[6];
  const float* w_att  = (const float*)d_in[7];
  const float* b_att  = (const float*)d_in[8];
  const float* emb    = (const float*)d_in[9];
  const float* W_ih   = (const float*)d_in[10];
  const float* b_ih   = (const float*)d_in[11];
  const float* W_hh   = (const float*)d_in[12];
  const float* b_hh   = (const float*)d_in[13];
  const float* W_h0   = (const float*)d_in[14];
  const float* b_h0   = (const float*)d_in[15];
  const float* W_c0   = (const float*)d_in[16];
  const float* b_c0   = (const float*)d_in[17];
  const float* W_beta = (const float*)d_in[18];
  const float* b_beta = (const float*)d_in[19];
  const float* W_fc   = (const float*)d_in[20];
  const float* b_fc   = (const float*)d_in[21];

  float* ws     = (float*)d_ws;
  float* preds  = (float*)d_out;                   // [B][ML][V]
  float* alphas = preds + (size_t)NB * NML * NV;   // [B][ML][L]

  float* mean_enc = ws + WS_MEAN;
  float* h        = ws + WS_H;
  float* c        = ws + WS_C;
  float* alpha    = ws + WS_ALPH;
  float* P        = ws + WS_P;
  short* h_bf     = (short*)(ws + WS_HBF);
  short* xcat     = (short*)(ws + WS_XCAT);
  short* e_proj   = (short*)(ws + WS_EPB);
  short* We_t     = (short*)(ws + WS_WET);
  short* Wihh_t   = (short*)(ws + WS_WIHT);
  short* Wfc_t    = (short*)(ws + WS_WFCT);

  // one-time transposed bf16 weights: dst[n][k]
  k_tcvt<<<dim3(NA / 32, NE / 32), dim3(32, 8), 0, stream>>>(W_enc, NE, NA, We_t, NE, 0);
  k_tcvt<<<dim3(NG / 32, (NM + NE) / 32), dim3(32, 8), 0, stream>>>(W_ih, NM + NE, NG, Wihh_t, KX, 0);
  k_tcvt<<<dim3(NG / 32, ND / 32), dim3(32, 8), 0, stream>>>(W_hh, ND, NG, Wihh_t, KX, NM + NE);
  k_tcvt<<<dim3((NV + 31) / 32, ND / 32), dim3(32, 8), 0, stream>>>(W_fc, ND, NV, Wfc_t, ND, 0);

  k_mean<<<(NB * NE) / 256, 256, 0, stream>>>(enc, mean_enc);
  k_init<<<(NB * ND) / 256, 256, 0, stream>>>(mean_enc, W_h0, b_h0, W_c0, b_c0, h, c, h_bf, xcat);
  k_eproj<<<dim3((NB * NL) / 128, NA / 64), 256, 0, stream>>>(enc, We_t, b_enc, e_proj);

  for (int t = 0; t < NML; ++t) {
    k_att<<<NB, 512, 0, stream>>>(h, W_dec, b_dec, e_proj, w_att, b_att, clen, caps, emb,
                                  alpha, alphas, xcat, t);
    k_ctxgate<<<dim3(NE / 256, NB / 4), 256, 0, stream>>>(enc, alpha, h, W_beta, b_beta, xcat);
    k_gates<<<dim3(NG / 128, KSPL), 256, 0, stream>>>(xcat, Wihh_t, P);
    k_lstm<<<(NB * ND) / 256, 256, 0, stream>>>(P, b_ih, b_hh, h, c, h_bf, xcat);
    k_pred<<<(NV + 127) / 128, 256, 0, stream>>>(h_bf, Wfc_t, b_fc, clen, preds, t);
  }
}

// Round 3
// 1704.402 us; speedup vs baseline: 2.6404x; 1.8137x over previous
//
#include <hip/hip_runtime.h>
#include <math.h>

namespace {

constexpr int NB  = 64;     // batch
constexpr int NL  = 196;    // L
constexpr int NE  = 2048;   // E
constexpr int ND  = 512;    // D
constexpr int NA  = 512;    // A
constexpr int NM  = 512;    // M
constexpr int NV  = 30000;  // vocab
constexpr int NT  = 21;     // T
constexpr int NML = 20;     // max_len
constexpr int NG  = 4 * ND;           // 2048
constexpr int KXG = NM + NE;          // 2560 (gates GEMM K: [emb | gctx])
constexpr int KSPL = 8, KSL = KXG / KSPL;  // 320 = 5 x 64
// fused h-GEMM N-space: [d (512) | gate (2048) | hWhh (2048) | pred (30000)]
constexpr int NALL = ND + NE + NG + NV;    // 34608
constexpr int OFF_GATE = ND;               // 512
constexpr int OFF_HWHH = ND + NE;          // 2560
constexpr int OFF_PRED = ND + NE + NG;     // 4608

// ---- workspace layout ----
constexpr size_t WS_MEAN = 0;                                  // [64][2048] f32
constexpr size_t WS_H    = WS_MEAN + (size_t)NB * NE;
constexpr size_t WS_C    = WS_H    + (size_t)NB * ND;
constexpr size_t WS_D    = WS_C    + (size_t)NB * ND;          // [64][512]
constexpr size_t WS_GATE = WS_D    + (size_t)NB * NA;          // [64][2048] sigmoid applied
constexpr size_t WS_HWHH = WS_GATE + (size_t)NB * NE;          // [64][2048]
constexpr size_t WS_EN   = WS_HWHH + (size_t)NB * NG;          // [64][196]
constexpr size_t WS_PP   = WS_EN   + (size_t)NB * NL;          // 1048576 (init partials / gates partials)
constexpr size_t WS_SHB  = WS_PP   + (size_t)1048576;          // short region start
constexpr size_t SH_HBF  = 0;                                  // [64][512] bf16
constexpr size_t SH_XEMB = SH_HBF  + (size_t)NB * ND;          // [20][64][512]
constexpr size_t SH_GCTX = SH_XEMB + (size_t)NML * NB * NM;    // [64][2048]
constexpr size_t SH_EPROJ= SH_GCTX + (size_t)NB * NE;          // [12544][512]
constexpr size_t SH_WET  = SH_EPROJ+ (size_t)NB * NL * NA;     // [512][2048]
constexpr size_t SH_WIHX = SH_WET  + (size_t)NA * NE;          // [2048][2560]
constexpr size_t SH_WALL = SH_WIHX + (size_t)NG * KXG;         // [34608][512]
constexpr size_t SH_ENCBF= SH_WALL + (size_t)NALL * ND;        // [64][196][2048] optional
constexpr size_t SH_END  = SH_ENCBF+ (size_t)NB * NL * NE;
constexpr size_t BYTES_ENC = WS_SHB * 4 + SH_END * 2;

typedef __attribute__((ext_vector_type(8))) short short8v;
typedef __attribute__((ext_vector_type(4))) float f32x4;

__device__ __forceinline__ float sigmoidf_(float x) { return 1.f / (1.f + expf(-x)); }
__device__ __forceinline__ short f2bf(float f) {
  unsigned u = __float_as_uint(f);
  return (short)((u + 0x7FFFu + ((u >> 16) & 1u)) >> 16);
}
__device__ __forceinline__ float bf2f(short s) {
  return __uint_as_float(((unsigned)(unsigned short)s) << 16);
}

// ---------- MFMA building blocks (LDS [row][64k] bf16, chunk slot = kblk ^ (row&7)) ----------

template <int R>
__device__ __forceinline__ void stage_bf16(const short* __restrict__ src, int ldK,
                                           int rowClamp, short* lds, int tid) {
#pragma unroll
  for (int cidx = tid; cidx < R * 8; cidx += 256) {
    int row = cidx >> 3, kb = cidx & 7;
    int r = row < rowClamp ? row : rowClamp;
    int4 v = *(const int4*)(src + (size_t)r * ldK + kb * 8);
    *(int4*)(lds + row * 64 + ((kb ^ (row & 7)) << 3)) = v;
  }
}

template <int R>
__device__ __forceinline__ void stage_f32cvt(const float* __restrict__ src, int ldK,
                                             short* lds, int tid) {
#pragma unroll
  for (int cidx = tid; cidx < R * 8; cidx += 256) {
    int row = cidx >> 3, kb = cidx & 7;
    const float* p = src + (size_t)row * ldK + kb * 8;
    float4 x = *(const float4*)p;
    float4 y = *(const float4*)(p + 4);
    short8v s;
    s[0] = f2bf(x.x); s[1] = f2bf(x.y); s[2] = f2bf(x.z); s[3] = f2bf(x.w);
    s[4] = f2bf(y.x); s[5] = f2bf(y.y); s[6] = f2bf(y.z); s[7] = f2bf(y.w);
    *(short8v*)(lds + row * 64 + ((kb ^ (row & 7)) << 3)) = s;
  }
}

template <int FM, int FN>
__device__ __forceinline__ void mma_tiles(const short* ldsA, const short* ldsB,
                                          int wr, int wc, int lane, f32x4 acc[FM][FN]) {
  int l15 = lane & 15;
#pragma unroll
  for (int kk = 0; kk < 2; ++kk) {
    int kb0 = kk * 4 + (lane >> 4);
    short8v a[FM], b[FN];
#pragma unroll
    for (int m = 0; m < FM; ++m) {
      int row = wr * FM * 16 + m * 16 + l15;
      a[m] = *(const short8v*)(ldsA + row * 64 + ((kb0 ^ (row & 7)) << 3));
    }
#pragma unroll
    for (int n = 0; n < FN; ++n) {
      int row = wc * FN * 16 + n * 16 + l15;
      b[n] = *(const short8v*)(ldsB + row * 64 + ((kb0 ^ (row & 7)) << 3));
    }
#pragma unroll
    for (int m = 0; m < FM; ++m)
#pragma unroll
      for (int n = 0; n < FN; ++n)
        acc[m][n] = __builtin_amdgcn_mfma_f32_16x16x32_bf16(a[m], b[n], acc[m][n], 0, 0, 0);
  }
}

// ---------- one-time kernels ----------

__global__ __launch_bounds__(256) void k_tcvt(const float* __restrict__ src, int Ks, int Ns,
                                              short* __restrict__ dst, int ldDst, int kOff) {
  __shared__ float tbuf[32][33];
  int n0 = blockIdx.x * 32, k0 = blockIdx.y * 32;
  int tx = threadIdx.x, ty = threadIdx.y;  // 32 x 8
#pragma unroll
  for (int i = 0; i < 32; i += 8) {
    int k = k0 + ty + i, n = n0 + tx;
    tbuf[ty + i][tx] = (k < Ks && n < Ns) ? src[(size_t)k * Ns + n] : 0.f;
  }
  __syncthreads();
#pragma unroll
  for (int i = 0; i < 32; i += 8) {
    int n = n0 + ty + i, k = k0 + tx;
    if (n < Ns && k < Ks) dst[(size_t)n * ldDst + kOff + k] = f2bf(tbuf[tx][ty + i]);
  }
}

__global__ void k_encbf(const float* __restrict__ enc, short* __restrict__ encbf) {
  size_t i = ((size_t)blockIdx.x * 256 + threadIdx.x) * 8;
  float4 a = *(const float4*)(enc + i), b = *(const float4*)(enc + i + 4);
  short8v s;
  s[0] = f2bf(a.x); s[1] = f2bf(a.y); s[2] = f2bf(a.z); s[3] = f2bf(a.w);
  s[4] = f2bf(b.x); s[5] = f2bf(b.y); s[6] = f2bf(b.z); s[7] = f2bf(b.w);
  *(short8v*)(encbf + i) = s;
}

__global__ void k_xemb(const int* __restrict__ caps, const float* __restrict__ emb,
                       short* __restrict__ xemb) {
  int i = blockIdx.x * 256 + threadIdx.x;
  int m = i & (NM - 1), b = (i >> 9) & (NB - 1), t = i >> 15;
  xemb[i] = f2bf(emb[(size_t)caps[b * NT + t] * NM + m]);
}

__global__ void k_mean(const float* __restrict__ enc, float* __restrict__ mean_enc) {
  int idx = blockIdx.x * 256 + threadIdx.x;  // b*2048 + e
  int b = idx >> 11, e = idx & (NE - 1);
  const float* p = enc + (size_t)b * NL * NE + e;
  float s = 0.f;
  for (int l = 0; l < NL; ++l) s += p[(size_t)l * NE];
  mean_enc[idx] = s * (1.f / NL);
}

// h0/c0 partials: 16-way K-split. grid (256, 16)
__global__ void k_init0(const float* __restrict__ mean_enc, const float* __restrict__ W_h0,
                        const float* __restrict__ W_c0, float* __restrict__ PP) {
  int idx = blockIdx.x * 256 + threadIdx.x;  // b*1024 + half*512 + j
  int ks = blockIdx.y;
  int b = idx >> 10, jh = idx & 1023, half = jh >> 9, j = jh & 511;
  const float* W = half ? W_c0 : W_h0;
  const float* mp = mean_enc + (size_t)b * NE + ks * 128;
  const float* Wp = W + (size_t)(ks * 128) * ND + j;
  float acc = 0.f;
#pragma unroll 4
  for (int k = 0; k < 128; ++k) acc = fmaf(mp[k], Wp[(size_t)k * ND], acc);
  PP[(size_t)ks * 65536 + idx] = acc;
}

__global__ void k_init1(const float* __restrict__ PP, const float* __restrict__ b_h0,
                        const float* __restrict__ b_c0, float* __restrict__ h,
                        float* __restrict__ c, short* __restrict__ h_bf) {
  int idx = blockIdx.x * 256 + threadIdx.x;  // b*512 + j
  int b = idx >> 9, j = idx & 511;
  float ah = b_h0[j], ac = b_c0[j];
  for (int s = 0; s < 16; ++s) {
    const float* p = PP + (size_t)s * 65536 + b * 1024;
    ah += p[j]; ac += p[512 + j];
  }
  float hv = tanhf(ah), cv = tanhf(ac);
  h[idx] = hv; c[idx] = cv; h_bf[idx] = f2bf(hv);
}

// e_proj = enc @ W_enc + b_enc (bf16 out). grid (98, 8)
__global__ __launch_bounds__(256) void k_eproj(const float* __restrict__ enc,
                                               const short* __restrict__ We_t,
                                               const float* __restrict__ b_enc,
                                               short* __restrict__ e_proj) {
  constexpr int FM = 4, FN = 2;  // 128 x 64
  __shared__ short ldsA[128 * 64], ldsB[64 * 64];
  int bm = blockIdx.x * 128, bn = blockIdx.y * 64;
  int tid = threadIdx.x, lane = tid & 63, wave = tid >> 6, wr = wave >> 1, wc = wave & 1;
  f32x4 acc[FM][FN];
#pragma unroll
  for (int m = 0; m < FM; ++m)
#pragma unroll
    for (int n = 0; n < FN; ++n) acc[m][n] = (f32x4){0.f, 0.f, 0.f, 0.f};
  for (int k0 = 0; k0 < NE; k0 += 64) {
    __syncthreads();
    stage_f32cvt<128>(enc + (size_t)bm * NE + k0, NE, ldsA, tid);
    stage_bf16<64>(We_t + (size_t)bn * NE + k0, NE, 63, ldsB, tid);
    __syncthreads();
    mma_tiles<FM, FN>(ldsA, ldsB, wr, wc, lane, acc);
  }
#pragma unroll
  for (int m = 0; m < FM; ++m)
#pragma unroll
    for (int n = 0; n < FN; ++n) {
      int col = bn + wc * FN * 16 + n * 16 + (lane & 15);
      float bias = b_enc[col];
#pragma unroll
      for (int r = 0; r < 4; ++r) {
        int row = bm + wr * FM * 16 + m * 16 + (lane >> 4) * 4 + r;
        e_proj[(size_t)row * NA + col] = f2bf(acc[m][n][r] + bias);
      }
    }
}

// fused h-GEMM: h_bf [64,512] @ Wall_t^T -> d | gate | hWhh | preds(t)
__global__ __launch_bounds__(256) void k_hgemm(const short* __restrict__ h_bf,
                                               const short* __restrict__ Wall_t,
                                               const float* __restrict__ b_dec,
                                               const float* __restrict__ b_beta,
                                               const float* __restrict__ b_fc,
                                               const int* __restrict__ clen,
                                               float* __restrict__ d_buf,
                                               float* __restrict__ gate,
                                               float* __restrict__ hWhh,
                                               float* __restrict__ preds, int t) {
  constexpr int FM = 2, FN = 4;  // 64 x 128
  __shared__ short ldsA[64 * 64], ldsB[128 * 64];
  int bn = blockIdx.x * 128;
  int tid = threadIdx.x, lane = tid & 63, wave = tid >> 6, wr = wave >> 1, wc = wave & 1;
  int rowClampB = NALL - 1 - bn; if (rowClampB > 127) rowClampB = 127;
  f32x4 acc[FM][FN];
#pragma unroll
  for (int m = 0; m < FM; ++m)
#pragma unroll
    for (int n = 0; n < FN; ++n) acc[m][n] = (f32x4){0.f, 0.f, 0.f, 0.f};
  for (int k0 = 0; k0 < ND; k0 += 64) {
    __syncthreads();
    stage_bf16<64>(h_bf + k0, ND, 63, ldsA, tid);
    stage_bf16<128>(Wall_t + (size_t)bn * ND + k0, ND, rowClampB, ldsB, tid);
    __syncthreads();
    mma_tiles<FM, FN>(ldsA, ldsB, wr, wc, lane, acc);
  }
#pragma unroll
  for (int m = 0; m < FM; ++m)
#pragma unroll
    for (int r = 0; r < 4; ++r) {
      int row = wr * FM * 16 + m * 16 + (lane >> 4) * 4 + r;  // batch
      float mf = ((clen[row] - 1) > t) ? 1.f : 0.f;
#pragma unroll
      for (int n = 0; n < FN; ++n) {
        int col = bn + wc * FN * 16 + n * 16 + (lane & 15);
        float a = acc[m][n][r];
        if (bn < OFF_GATE) {
          d_buf[(size_t)row * NA + col] = a + b_dec[col];
        } else if (bn < OFF_HWHH) {
          int e = col - OFF_GATE;
          gate[(size_t)row * NE + e] = sigmoidf_(a + b_beta[e]);
        } else if (bn < OFF_PRED) {
          hWhh[(size_t)row * NG + (col - OFF_HWHH)] = a;
        } else {
          int v = col - OFF_PRED;
          if (v < NV) preds[((size_t)row * NML + t) * NV + v] = mf * (a + b_fc[v]);
        }
      }
    }
}

// ---------- per-step kernels ----------

__global__ __launch_bounds__(256) void k_energy(const short* __restrict__ e_proj,
                                                const float* __restrict__ d_buf,
                                                const float* __restrict__ w_att,
                                                const float* __restrict__ b_att,
                                                float* __restrict__ energy) {
  int tid = threadIdx.x, wave = tid >> 6, lane = tid & 63;
  int row = blockIdx.x * 4 + wave;  // b*196 + l
  int b = row / NL;
  short8v ev = *(const short8v*)(e_proj + (size_t)row * NA + lane * 8);
  const float* dp = d_buf + (size_t)b * NA + lane * 8;
  float4 d0 = *(const float4*)dp, d1 = *(const float4*)(dp + 4);
  const float* wp = w_att + lane * 8;
  float4 w0 = *(const float4*)wp, w1 = *(const float4*)(wp + 4);
  float dd[8] = {d0.x, d0.y, d0.z, d0.w, d1.x, d1.y, d1.z, d1.w};
  float ww[8] = {w0.x, w0.y, w0.z, w0.w, w1.x, w1.y, w1.z, w1.w};
  float acc = 0.f;
#pragma unroll
  for (int i = 0; i < 8; ++i) {
    float v = bf2f(ev[i]) + dd[i];
    acc = fmaf(fmaxf(v, 0.f), ww[i], acc);
  }
#pragma unroll
  for (int off = 32; off; off >>= 1) acc += __shfl_down(acc, off);
  if (lane == 0) energy[row] = acc + b_att[0];
}

template <bool BF>
__global__ __launch_bounds__(256) void k_ctx(const short* __restrict__ encbf,
                                             const float* __restrict__ encf,
                                             const float* __restrict__ energy,
                                             const float* __restrict__ gate,
                                             const int* __restrict__ clen,
                                             short* __restrict__ gctx,
                                             float* __restrict__ alphas_out, int t) {
  int b = blockIdx.y, e0 = blockIdx.x * 256, tid = threadIdx.x;
  __shared__ float al[NL];
  __shared__ float red[8];
  int wave = tid >> 6, lane = tid & 63;
  float v = (tid < NL) ? energy[b * NL + tid] : -INFINITY;
  float mx = v;
#pragma unroll
  for (int off = 32; off; off >>= 1) mx = fmaxf(mx, __shfl_down(mx, off));
  if (lane == 0) red[wave] = mx;
  __syncthreads();
  if (tid == 0) red[0] = fmaxf(fmaxf(red[0], red[1]), fmaxf(red[2], red[3]));
  __syncthreads();
  mx = red[0];
  float ex = (tid < NL) ? expf(v - mx) : 0.f;
  float sm = ex;
#pragma unroll
  for (int off = 32; off; off >>= 1) sm += __shfl_down(sm, off);
  if (lane == 0) red[4 + wave] = sm;
  __syncthreads();
  if (tid == 0) red[0] = 1.f / (red[4] + red[5] + red[6] + red[7]);
  __syncthreads();
  float alv = ex * red[0];
  if (tid < NL) {
    al[tid] = alv;
    if (blockIdx.x == 0) {
      float mf = ((clen[b] - 1) > t) ? 1.f : 0.f;
      alphas_out[((size_t)b * NML + t) * NL + tid] = alv * mf;
    }
  }
  __syncthreads();
  float cx = 0.f;
  if (BF) {
    const short* p = encbf + (size_t)b * NL * NE + e0 + tid;
#pragma unroll 4
    for (int l = 0; l < NL; ++l) cx = fmaf(al[l], bf2f(p[(size_t)l * NE]), cx);
  } else {
    const float* p = encf + (size_t)b * NL * NE + e0 + tid;
#pragma unroll 4
    for (int l = 0; l < NL; ++l) cx = fmaf(al[l], p[(size_t)l * NE], cx);
  }
  int e = e0 + tid;
  gctx[(size_t)b * NE + e] = f2bf(cx * gate[(size_t)b * NE + e]);
}

// gates partial GEMM: [emb_t | gctx] @ Wihx_t^T -> P[ks][64][2048]. grid (16, 8)
__global__ __launch_bounds__(256) void k_gates(const short* __restrict__ xemb_t,
                                               const short* __restrict__ gctx,
                                               const short* __restrict__ Wihx_t,
                                               float* __restrict__ P) {
  constexpr int FM = 2, FN = 4;  // 64 x 128
  __shared__ short ldsA[64 * 64], ldsB[128 * 64];
  int bn = blockIdx.x * 128, ks = blockIdx.y;
  int tid = threadIdx.x, lane = tid & 63, wave = tid >> 6, wr = wave >> 1, wc = wave & 1;
  f32x4 acc[FM][FN];
#pragma unroll
  for (int m = 0; m < FM; ++m)
#pragma unroll
    for (int n = 0; n < FN; ++n) acc[m][n] = (f32x4){0.f, 0.f, 0.f, 0.f};
  int kend = (ks + 1) * KSL;
  for (int k0 = ks * KSL; k0 < kend; k0 += 64) {
    __syncthreads();
    if (k0 < NM) stage_bf16<64>(xemb_t + k0, NM, 63, ldsA, tid);
    else         stage_bf16<64>(gctx + (k0 - NM), NE, 63, ldsA, tid);
    stage_bf16<128>(Wihx_t + (size_t)bn * KXG + k0, KXG, 127, ldsB, tid);
    __syncthreads();
    mma_tiles<FM, FN>(ldsA, ldsB, wr, wc, lane, acc);
  }
#pragma unroll
  for (int m = 0; m < FM; ++m)
#pragma unroll
    for (int n = 0; n < FN; ++n) {
      int col = bn + wc * FN * 16 + n * 16 + (lane & 15);
#pragma unroll
      for (int r = 0; r < 4; ++r) {
        int row = wr * FM * 16 + m * 16 + (lane >> 4) * 4 + r;
        P[((size_t)ks * NB + row) * NG + col] = acc[m][n][r];
      }
    }
}

__global__ void k_lstm(const float* __restrict__ P, const float* __restrict__ hWhh,
                       const float* __restrict__ b_ih, const float* __restrict__ b_hh,
                       float* __restrict__ h, float* __restrict__ c,
                       short* __restrict__ h_bf) {
  int idx = blockIdx.x * 256 + threadIdx.x;  // b*512 + j
  int b = idx >> 9, j = idx & (ND - 1);
  const float* hw = hWhh + (size_t)b * NG;
  float gi = b_ih[j] + b_hh[j] + hw[j];
  float gf = b_ih[j + ND] + b_hh[j + ND] + hw[j + ND];
  float gg = b_ih[j + 2 * ND] + b_hh[j + 2 * ND] + hw[j + 2 * ND];
  float go = b_ih[j + 3 * ND] + b_hh[j + 3 * ND] + hw[j + 3 * ND];
  for (int s = 0; s < KSPL; ++s) {
    const float* Pp = P + ((size_t)s * NB + b) * NG;
    gi += Pp[j]; gf += Pp[j + ND]; gg += Pp[j + 2 * ND]; go += Pp[j + 3 * ND];
  }
  float cn = sigmoidf_(gf) * c[idx] + sigmoidf_(gi) * tanhf(gg);
  float hn = sigmoidf_(go) * tanhf(cn);
  c[idx] = cn;
  h[idx] = hn;
  h_bf[idx] = f2bf(hn);
}

}  // namespace

extern "C" void kernel_launch(void* const* d_in, const int* in_sizes, int n_in,
                              void* d_out, int out_size, void* d_ws, size_t ws_size,
                              hipStream_t stream) {
  (void)in_sizes; (void)n_in; (void)out_size;
  const float* enc    = (const float*)d_in[0];
  const int*   caps   = (const int*)d_in[1];
  const int*   clen   = (const int*)d_in[2];
  const float* W_enc  = (const float*)d_in[3];
  const float* b_enc  = (const float*)d_in[4];
  const float* W_dec  = (const float*)d_in[5];
  const float* b_dec  = (const float*)d_in[6];
  const float* w_att  = (const float*)d_in[7];
  const float* b_att  = (const float*)d_in[8];
  const float* emb    = (const float*)d_in[9];
  const float* W_ih   = (const float*)d_in[10];
  const float* b_ih   = (const float*)d_in[11];
  const float* W_hh   = (const float*)d_in[12];
  const float* b_hh   = (const float*)d_in[13];
  const float* W_h0   = (const float*)d_in[14];
  const float* b_h0   = (const float*)d_in[15];
  const float* W_c0   = (const float*)d_in[16];
  const float* b_c0   = (const float*)d_in[17];
  const float* W_beta = (const float*)d_in[18];
  const float* b_beta = (const float*)d_in[19];
  const float* W_fc   = (const float*)d_in[20];
  const float* b_fc   = (const float*)d_in[21];

  float* ws     = (float*)d_ws;
  float* preds  = (float*)d_out;                   // [B][ML][V]
  float* alphas = preds + (size_t)NB * NML * NV;   // [B][ML][L]

  float* mean_enc = ws + WS_MEAN;
  float* h        = ws + WS_H;
  float* c        = ws + WS_C;
  float* d_buf    = ws + WS_D;
  float* gate     = ws + WS_GATE;
  float* hWhh     = ws + WS_HWHH;
  float* energy   = ws + WS_EN;
  float* PP       = ws + WS_PP;
  short* shb      = (short*)(ws + WS_SHB);
  short* h_bf     = shb + SH_HBF;
  short* xemb     = shb + SH_XEMB;
  short* gctx     = shb + SH_GCTX;
  short* e_proj   = shb + SH_EPROJ;
  short* We_t     = shb + SH_WET;
  short* Wihx_t   = shb + SH_WIHX;
  short* Wall_t   = shb + SH_WALL;
  short* encbf    = shb + SH_ENCBF;
  const bool use_bf = ws_size >= BYTES_ENC;

  // one-time weight transposes (dst[n][k] bf16)
  k_tcvt<<<dim3(NA / 32, NE / 32), dim3(32, 8), 0, stream>>>(W_enc, NE, NA, We_t, NE, 0);
  k_tcvt<<<dim3(NG / 32, KXG / 32), dim3(32, 8), 0, stream>>>(W_ih, KXG, NG, Wihx_t, KXG, 0);
  k_tcvt<<<dim3(NA / 32, ND / 32), dim3(32, 8), 0, stream>>>(W_dec, ND, NA, Wall_t, ND, 0);
  k_tcvt<<<dim3(NE / 32, ND / 32), dim3(32, 8), 0, stream>>>(
      W_beta, ND, NE, Wall_t + (size_t)OFF_GATE * ND, ND, 0);
  k_tcvt<<<dim3(NG / 32, ND / 32), dim3(32, 8), 0, stream>>>(
      W_hh, ND, NG, Wall_t + (size_t)OFF_HWHH * ND, ND, 0);
  k_tcvt<<<dim3((NV + 31) / 32, ND / 32), dim3(32, 8), 0, stream>>>(
      W_fc, ND, NV, Wall_t + (size_t)OFF_PRED * ND, ND, 0);
  if (use_bf)
    k_encbf<<<(int)((size_t)NB * NL * NE / 2048), 256, 0, stream>>>(enc, encbf);
  k_xemb<<<(NML * NB * NM) / 256, 256, 0, stream>>>(caps, emb, xemb);

  k_mean<<<(NB * NE) / 256, 256, 0, stream>>>(enc, mean_enc);
  k_init0<<<dim3(256, 16), 256, 0, stream>>>(mean_enc, W_h0, W_c0, PP);
  k_init1<<<(NB * ND) / 256, 256, 0, stream>>>(PP, b_h0, b_c0, h, c, h_bf);
  k_eproj<<<dim3((NB * NL) / 128, NA / 64), 256, 0, stream>>>(enc, We_t, b_enc, e_proj);
  // h0-dependent projections only (d, gate, hWhh): first 36 column-blocks
  k_hgemm<<<OFF_PRED / 128, 256, 0, stream>>>(h_bf, Wall_t, b_dec, b_beta, b_fc, clen,
                                              d_buf, gate, hWhh, preds, 0);

  for (int t = 0; t < NML; ++t) {
    k_energy<<<(NB * NL) / 4, 256, 0, stream>>>(e_proj, d_buf, w_att, b_att, energy);
    if (use_bf)
      k_ctx<true><<<dim3(NE / 256, NB), 256, 0, stream>>>(encbf, enc, energy, gate, clen,
                                                          gctx, alphas, t);
    else
      k_ctx<false><<<dim3(NE / 256, NB), 256, 0, stream>>>(encbf, enc, energy, gate, clen,
                                                           gctx, alphas, t);
    k_gates<<<dim3(NG / 128, KSPL), 256, 0, stream>>>(xemb + (size_t)t * NB * NM, gctx,
                                                      Wihx_t, PP);
    k_lstm<<<(NB * ND) / 256, 256, 0, stream>>>(PP, hWhh, b_ih, b_hh, h, c, h_bf);
    // fused: preds(t) + d/gate/hWhh for step t+1
    k_hgemm<<<(NALL + 127) / 128, 256, 0, stream>>>(h_bf, Wall_t, b_dec, b_beta, b_fc, clen,
                                                    d_buf, gate, hWhh, preds, t);
  }
}

// Round 4
// 1347.176 us; speedup vs baseline: 3.3405x; 1.2652x over previous
//
#include <hip/hip_runtime.h>
#include <math.h>

namespace {

constexpr int NB  = 64;     // batch
constexpr int NL  = 196;    // L
constexpr int NE  = 2048;   // E
constexpr int ND  = 512;    // D
constexpr int NA  = 512;    // A
constexpr int NM  = 512;    // M
constexpr int NV  = 30000;  // vocab
constexpr int NT  = 21;     // T
constexpr int NML = 20;     // max_len
constexpr int NG  = 4 * ND;           // 2048
constexpr int KXG = NM + NE;          // 2560 (gates GEMM K: [emb | gctx])
constexpr int KSPL = 8, KSL = KXG / KSPL;  // 320 = 5 x 64
// fused h-GEMM N-space: [d (512) | gate (2048) | hWhh (2048) | pred (30000)]
constexpr int NALL = ND + NE + NG + NV;    // 34608
constexpr int OFF_GATE = ND;               // 512
constexpr int OFF_HWHH = ND + NE;          // 2560
constexpr int OFF_PRED = ND + NE + NG;     // 4608

// ---- workspace layout ----
constexpr size_t WS_MEAN = 0;                                  // [64][2048] f32
constexpr size_t WS_H    = WS_MEAN + (size_t)NB * NE;
constexpr size_t WS_C    = WS_H    + (size_t)NB * ND;
constexpr size_t WS_D    = WS_C    + (size_t)NB * ND;          // [64][512]
constexpr size_t WS_GATE = WS_D    + (size_t)NB * NA;          // [64][2048] sigmoid applied
constexpr size_t WS_HWHH = WS_GATE + (size_t)NB * NE;          // [64][2048]
constexpr size_t WS_EN   = WS_HWHH + (size_t)NB * NG;          // [64][196]
constexpr size_t WS_PP   = WS_EN   + (size_t)NB * NL;          // 1048576 (init/gates partials)
constexpr size_t WS_SHB  = WS_PP   + (size_t)1048576;          // short region start
constexpr size_t SH_HBF  = 0;                                  // [64][512] bf16
constexpr size_t SH_XEMB = SH_HBF  + (size_t)NB * ND;          // [20][64][512]
constexpr size_t SH_GCTX = SH_XEMB + (size_t)NML * NB * NM;    // [64][2048]
constexpr size_t SH_EPROJ= SH_GCTX + (size_t)NB * NE;          // [12544][512]
constexpr size_t SH_WET  = SH_EPROJ+ (size_t)NB * NL * NA;     // [512][2048]
constexpr size_t SH_WIHX = SH_WET  + (size_t)NA * NE;          // [2048][2560]
constexpr size_t SH_WALL = SH_WIHX + (size_t)NG * KXG;         // [34608][512]
constexpr size_t SH_ENCBF= SH_WALL + (size_t)NALL * ND;        // [64][196][2048] optional
constexpr size_t SH_END  = SH_ENCBF+ (size_t)NB * NL * NE;
constexpr size_t BYTES_ENC = WS_SHB * 4 + SH_END * 2;

typedef __attribute__((ext_vector_type(8))) short short8v;
typedef __attribute__((ext_vector_type(4))) float f32x4;

__device__ __forceinline__ float sigmoidf_(float x) { return 1.f / (1.f + expf(-x)); }
__device__ __forceinline__ short f2bf(float f) {
  unsigned u = __float_as_uint(f);
  return (short)((u + 0x7FFFu + ((u >> 16) & 1u)) >> 16);
}
__device__ __forceinline__ float bf2f(short s) {
  return __uint_as_float(((unsigned)(unsigned short)s) << 16);
}

// ---------- MFMA building blocks (LDS [row][64k] bf16, chunk slot = kblk ^ (row&7)) ----------

template <int R>
__device__ __forceinline__ void stage_bf16(const short* __restrict__ src, int ldK,
                                           int rowClamp, short* lds, int tid) {
#pragma unroll
  for (int cidx = tid; cidx < R * 8; cidx += 256) {
    int row = cidx >> 3, kb = cidx & 7;
    int r = row < rowClamp ? row : rowClamp;
    int4 v = *(const int4*)(src + (size_t)r * ldK + kb * 8);
    *(int4*)(lds + row * 64 + ((kb ^ (row & 7)) << 3)) = v;
  }
}

template <int R>
__device__ __forceinline__ void stage_f32cvt(const float* __restrict__ src, int ldK,
                                             short* lds, int tid) {
#pragma unroll
  for (int cidx = tid; cidx < R * 8; cidx += 256) {
    int row = cidx >> 3, kb = cidx & 7;
    const float* p = src + (size_t)row * ldK + kb * 8;
    float4 x = *(const float4*)p;
    float4 y = *(const float4*)(p + 4);
    short8v s;
    s[0] = f2bf(x.x); s[1] = f2bf(x.y); s[2] = f2bf(x.z); s[3] = f2bf(x.w);
    s[4] = f2bf(y.x); s[5] = f2bf(y.y); s[6] = f2bf(y.z); s[7] = f2bf(y.w);
    *(short8v*)(lds + row * 64 + ((kb ^ (row & 7)) << 3)) = s;
  }
}

template <int FM, int FN>
__device__ __forceinline__ void mma_tiles(const short* ldsA, const short* ldsB,
                                          int wr, int wc, int lane, f32x4 acc[FM][FN]) {
  int l15 = lane & 15;
#pragma unroll
  for (int kk = 0; kk < 2; ++kk) {
    int kb0 = kk * 4 + (lane >> 4);
    short8v a[FM], b[FN];
#pragma unroll
    for (int m = 0; m < FM; ++m) {
      int row = wr * FM * 16 + m * 16 + l15;
      a[m] = *(const short8v*)(ldsA + row * 64 + ((kb0 ^ (row & 7)) << 3));
    }
#pragma unroll
    for (int n = 0; n < FN; ++n) {
      int row = wc * FN * 16 + n * 16 + l15;
      b[n] = *(const short8v*)(ldsB + row * 64 + ((kb0 ^ (row & 7)) << 3));
    }
#pragma unroll
    for (int m = 0; m < FM; ++m)
#pragma unroll
      for (int n = 0; n < FN; ++n)
        acc[m][n] = __builtin_amdgcn_mfma_f32_16x16x32_bf16(a[m], b[n], acc[m][n], 0, 0, 0);
  }
}

// ---------- one-time kernels ----------

__global__ __launch_bounds__(256) void k_tcvt(const float* __restrict__ src, int Ks, int Ns,
                                              short* __restrict__ dst, int ldDst, int kOff) {
  __shared__ float tbuf[32][33];
  int n0 = blockIdx.x * 32, k0 = blockIdx.y * 32;
  int tx = threadIdx.x, ty = threadIdx.y;  // 32 x 8
#pragma unroll
  for (int i = 0; i < 32; i += 8) {
    int k = k0 + ty + i, n = n0 + tx;
    tbuf[ty + i][tx] = (k < Ks && n < Ns) ? src[(size_t)k * Ns + n] : 0.f;
  }
  __syncthreads();
#pragma unroll
  for (int i = 0; i < 32; i += 8) {
    int n = n0 + ty + i, k = k0 + tx;
    if (n < Ns && k < Ks) dst[(size_t)n * ldDst + kOff + k] = f2bf(tbuf[tx][ty + i]);
  }
}

// fused: encbf (optional) + column mean, single pass over enc. grid (8, 64)
template <bool BF>
__global__ __launch_bounds__(256) void k_prep(const float* __restrict__ enc,
                                              short* __restrict__ encbf,
                                              float* __restrict__ mean_enc) {
  int b = blockIdx.y;
  int e = blockIdx.x * 256 + threadIdx.x;
  const float* p = enc + (size_t)b * NL * NE + e;
  short* q = encbf + (size_t)b * NL * NE + e;
  float s = 0.f;
  for (int l = 0; l < NL; ++l) {
    float v = p[(size_t)l * NE];
    s += v;
    if (BF) q[(size_t)l * NE] = f2bf(v);
  }
  mean_enc[(size_t)b * NE + e] = s * (1.f / NL);
}

__global__ void k_xemb(const int* __restrict__ caps, const float* __restrict__ emb,
                       short* __restrict__ xemb) {
  int i = blockIdx.x * 256 + threadIdx.x;
  int m = i & (NM - 1), b = (i >> 9) & (NB - 1), t = i >> 15;
  xemb[i] = f2bf(emb[(size_t)caps[b * NT + t] * NM + m]);
}

// h0/c0 partials: 16-way K-split. grid (256, 16)
__global__ void k_init0(const float* __restrict__ mean_enc, const float* __restrict__ W_h0,
                        const float* __restrict__ W_c0, float* __restrict__ PP) {
  int idx = blockIdx.x * 256 + threadIdx.x;  // b*1024 + half*512 + j
  int ks = blockIdx.y;
  int b = idx >> 10, jh = idx & 1023, half = jh >> 9, j = jh & 511;
  const float* W = half ? W_c0 : W_h0;
  const float* mp = mean_enc + (size_t)b * NE + ks * 128;
  const float* Wp = W + (size_t)(ks * 128) * ND + j;
  float acc = 0.f;
#pragma unroll 4
  for (int k = 0; k < 128; ++k) acc = fmaf(mp[k], Wp[(size_t)k * ND], acc);
  PP[(size_t)ks * 65536 + idx] = acc;
}

__global__ void k_init1(const float* __restrict__ PP, const float* __restrict__ b_h0,
                        const float* __restrict__ b_c0, float* __restrict__ h,
                        float* __restrict__ c, short* __restrict__ h_bf) {
  int idx = blockIdx.x * 256 + threadIdx.x;  // b*512 + j
  int b = idx >> 9, j = idx & 511;
  float ah = b_h0[j], ac = b_c0[j];
  for (int s = 0; s < 16; ++s) {
    const float* p = PP + (size_t)s * 65536 + b * 1024;
    ah += p[j]; ac += p[512 + j];
  }
  float hv = tanhf(ah), cv = tanhf(ac);
  h[idx] = hv; c[idx] = cv; h_bf[idx] = f2bf(hv);
}

// e_proj = enc @ W_enc + b_enc (bf16 out). 128x128 tile, grid (98, 4)
template <bool BF>
__global__ __launch_bounds__(256) void k_eproj(const float* __restrict__ enc,
                                               const short* __restrict__ encbf,
                                               const short* __restrict__ We_t,
                                               const float* __restrict__ b_enc,
                                               short* __restrict__ e_proj) {
  constexpr int FM = 4, FN = 4;  // 128 x 128
  __shared__ short ldsA[128 * 64], ldsB[128 * 64];
  int bm = blockIdx.x * 128, bn = blockIdx.y * 128;
  int tid = threadIdx.x, lane = tid & 63, wave = tid >> 6, wr = wave >> 1, wc = wave & 1;
  f32x4 acc[FM][FN];
#pragma unroll
  for (int m = 0; m < FM; ++m)
#pragma unroll
    for (int n = 0; n < FN; ++n) acc[m][n] = (f32x4){0.f, 0.f, 0.f, 0.f};
  for (int k0 = 0; k0 < NE; k0 += 64) {
    __syncthreads();
    if (BF) stage_bf16<128>(encbf + (size_t)bm * NE + k0, NE, 127, ldsA, tid);
    else    stage_f32cvt<128>(enc + (size_t)bm * NE + k0, NE, ldsA, tid);
    stage_bf16<128>(We_t + (size_t)bn * NE + k0, NE, 127, ldsB, tid);
    __syncthreads();
    mma_tiles<FM, FN>(ldsA, ldsB, wr, wc, lane, acc);
  }
#pragma unroll
  for (int m = 0; m < FM; ++m)
#pragma unroll
    for (int n = 0; n < FN; ++n) {
      int col = bn + wc * FN * 16 + n * 16 + (lane & 15);
      float bias = b_enc[col];
#pragma unroll
      for (int r = 0; r < 4; ++r) {
        int row = bm + wr * FM * 16 + m * 16 + (lane >> 4) * 4 + r;
        e_proj[(size_t)row * NA + col] = f2bf(acc[m][n][r] + bias);
      }
    }
}

// fused h-GEMM: h_bf [64,512] @ Wall_t^T -> d | gate | hWhh | preds(t). 64x64 tile
__global__ __launch_bounds__(256) void k_hgemm(const short* __restrict__ h_bf,
                                               const short* __restrict__ Wall_t,
                                               const float* __restrict__ b_dec,
                                               const float* __restrict__ b_beta,
                                               const float* __restrict__ b_fc,
                                               const int* __restrict__ clen,
                                               float* __restrict__ d_buf,
                                               float* __restrict__ gate,
                                               float* __restrict__ hWhh,
                                               float* __restrict__ preds, int t) {
  constexpr int FM = 2, FN = 2;  // 64 x 64, 4 waves (2x2)
  __shared__ short ldsA[64 * 64], ldsB[64 * 64];
  int bn = blockIdx.x * 64;
  int tid = threadIdx.x, lane = tid & 63, wave = tid >> 6, wr = wave >> 1, wc = wave & 1;
  int rowClampB = NALL - 1 - bn; if (rowClampB > 63) rowClampB = 63;
  f32x4 acc[FM][FN];
#pragma unroll
  for (int m = 0; m < FM; ++m)
#pragma unroll
    for (int n = 0; n < FN; ++n) acc[m][n] = (f32x4){0.f, 0.f, 0.f, 0.f};
  for (int k0 = 0; k0 < ND; k0 += 64) {
    __syncthreads();
    stage_bf16<64>(h_bf + k0, ND, 63, ldsA, tid);
    stage_bf16<64>(Wall_t + (size_t)bn * ND + k0, ND, rowClampB, ldsB, tid);
    __syncthreads();
    mma_tiles<FM, FN>(ldsA, ldsB, wr, wc, lane, acc);
  }
#pragma unroll
  for (int m = 0; m < FM; ++m)
#pragma unroll
    for (int r = 0; r < 4; ++r) {
      int row = wr * FM * 16 + m * 16 + (lane >> 4) * 4 + r;  // batch
      float mf = ((clen[row] - 1) > t) ? 1.f : 0.f;
#pragma unroll
      for (int n = 0; n < FN; ++n) {
        int col = bn + wc * FN * 16 + n * 16 + (lane & 15);
        float a = acc[m][n][r];
        if (bn < OFF_GATE) {
          d_buf[(size_t)row * NA + col] = a + b_dec[col];
        } else if (bn < OFF_HWHH) {
          int e = col - OFF_GATE;
          gate[(size_t)row * NE + e] = sigmoidf_(a + b_beta[e]);
        } else if (bn < OFF_PRED) {
          hWhh[(size_t)row * NG + (col - OFF_HWHH)] = a;
        } else {
          int v = col - OFF_PRED;
          if (v < NV) preds[((size_t)row * NML + t) * NV + v] = mf * (a + b_fc[v]);
        }
      }
    }
}

// ---------- per-step kernels ----------

__global__ __launch_bounds__(256) void k_energy(const short* __restrict__ e_proj,
                                                const float* __restrict__ d_buf,
                                                const float* __restrict__ w_att,
                                                const float* __restrict__ b_att,
                                                float* __restrict__ energy) {
  int tid = threadIdx.x, wave = tid >> 6, lane = tid & 63;
  int row = blockIdx.x * 4 + wave;  // b*196 + l
  int b = row / NL;
  short8v ev = *(const short8v*)(e_proj + (size_t)row * NA + lane * 8);
  const float* dp = d_buf + (size_t)b * NA + lane * 8;
  float4 d0 = *(const float4*)dp, d1 = *(const float4*)(dp + 4);
  const float* wp = w_att + lane * 8;
  float4 w0 = *(const float4*)wp, w1 = *(const float4*)(wp + 4);
  float dd[8] = {d0.x, d0.y, d0.z, d0.w, d1.x, d1.y, d1.z, d1.w};
  float ww[8] = {w0.x, w0.y, w0.z, w0.w, w1.x, w1.y, w1.z, w1.w};
  float acc = 0.f;
#pragma unroll
  for (int i = 0; i < 8; ++i) {
    float v = bf2f(ev[i]) + dd[i];
    acc = fmaf(fmaxf(v, 0.f), ww[i], acc);
  }
#pragma unroll
  for (int off = 32; off; off >>= 1) acc += __shfl_down(acc, off);
  if (lane == 0) energy[row] = acc + b_att[0];
}

// softmax (per-block recompute) + ctx + gate -> gctx bf16. 2 e per thread. grid (4, 64)
template <bool BF>
__global__ __launch_bounds__(256) void k_ctx(const short* __restrict__ encbf,
                                             const float* __restrict__ encf,
                                             const float* __restrict__ energy,
                                             const float* __restrict__ gate,
                                             const int* __restrict__ clen,
                                             short* __restrict__ gctx,
                                             float* __restrict__ alphas_out, int t) {
  int b = blockIdx.y, e0 = blockIdx.x * 512, tid = threadIdx.x;
  __shared__ float al[NL];
  __shared__ float red[8];
  int wave = tid >> 6, lane = tid & 63;
  float v = (tid < NL) ? energy[b * NL + tid] : -INFINITY;
  float mx = v;
#pragma unroll
  for (int off = 32; off; off >>= 1) mx = fmaxf(mx, __shfl_down(mx, off));
  if (lane == 0) red[wave] = mx;
  __syncthreads();
  if (tid == 0) red[0] = fmaxf(fmaxf(red[0], red[1]), fmaxf(red[2], red[3]));
  __syncthreads();
  mx = red[0];
  float ex = (tid < NL) ? expf(v - mx) : 0.f;
  float sm = ex;
#pragma unroll
  for (int off = 32; off; off >>= 1) sm += __shfl_down(sm, off);
  if (lane == 0) red[4 + wave] = sm;
  __syncthreads();
  if (tid == 0) red[0] = 1.f / (red[4] + red[5] + red[6] + red[7]);
  __syncthreads();
  float alv = ex * red[0];
  if (tid < NL) {
    al[tid] = alv;
    if (blockIdx.x == 0) {
      float mf = ((clen[b] - 1) > t) ? 1.f : 0.f;
      alphas_out[((size_t)b * NML + t) * NL + tid] = alv * mf;
    }
  }
  __syncthreads();
  float cx0 = 0.f, cx1 = 0.f;
  if (BF) {
    const unsigned* p = (const unsigned*)(encbf + (size_t)b * NL * NE + e0) + tid;
#pragma unroll 4
    for (int l = 0; l < NL; ++l) {
      unsigned u = p[(size_t)l * (NE / 2)];
      cx0 = fmaf(al[l], bf2f((short)(u & 0xffffu)), cx0);
      cx1 = fmaf(al[l], bf2f((short)(u >> 16)), cx1);
    }
  } else {
    const float* p = encf + (size_t)b * NL * NE + e0 + 2 * tid;
#pragma unroll 4
    for (int l = 0; l < NL; ++l) {
      float2 u = *(const float2*)(p + (size_t)l * NE);
      cx0 = fmaf(al[l], u.x, cx0);
      cx1 = fmaf(al[l], u.y, cx1);
    }
  }
  int e = e0 + 2 * tid;
  const float* gp = gate + (size_t)b * NE + e;
  unsigned out = (unsigned)(unsigned short)f2bf(cx0 * gp[0]) |
                 ((unsigned)(unsigned short)f2bf(cx1 * gp[1]) << 16);
  *(unsigned*)(gctx + (size_t)b * NE + e) = out;
}

// gates partial GEMM: [emb_t | gctx] @ Wihx_t^T -> P[ks][64][2048]. 64x64, grid (32, 8)
__global__ __launch_bounds__(256) void k_gates(const short* __restrict__ xemb_t,
                                               const short* __restrict__ gctx,
                                               const short* __restrict__ Wihx_t,
                                               float* __restrict__ P) {
  constexpr int FM = 2, FN = 2;  // 64 x 64
  __shared__ short ldsA[64 * 64], ldsB[64 * 64];
  int bn = blockIdx.x * 64, ks = blockIdx.y;
  int tid = threadIdx.x, lane = tid & 63, wave = tid >> 6, wr = wave >> 1, wc = wave & 1;
  f32x4 acc[FM][FN];
#pragma unroll
  for (int m = 0; m < FM; ++m)
#pragma unroll
    for (int n = 0; n < FN; ++n) acc[m][n] = (f32x4){0.f, 0.f, 0.f, 0.f};
  int kend = (ks + 1) * KSL;
  for (int k0 = ks * KSL; k0 < kend; k0 += 64) {
    __syncthreads();
    if (k0 < NM) stage_bf16<64>(xemb_t + k0, NM, 63, ldsA, tid);
    else         stage_bf16<64>(gctx + (k0 - NM), NE, 63, ldsA, tid);
    stage_bf16<64>(Wihx_t + (size_t)bn * KXG + k0, KXG, 63, ldsB, tid);
    __syncthreads();
    mma_tiles<FM, FN>(ldsA, ldsB, wr, wc, lane, acc);
  }
#pragma unroll
  for (int m = 0; m < FM; ++m)
#pragma unroll
    for (int n = 0; n < FN; ++n) {
      int col = bn + wc * FN * 16 + n * 16 + (lane & 15);
#pragma unroll
      for (int r = 0; r < 4; ++r) {
        int row = wr * FM * 16 + m * 16 + (lane >> 4) * 4 + r;
        P[((size_t)ks * NB + row) * NG + col] = acc[m][n][r];
      }
    }
}

__global__ void k_lstm(const float* __restrict__ P, const float* __restrict__ hWhh,
                       const float* __restrict__ b_ih, const float* __restrict__ b_hh,
                       float* __restrict__ h, float* __restrict__ c,
                       short* __restrict__ h_bf) {
  int idx = blockIdx.x * 256 + threadIdx.x;  // b*512 + j
  int b = idx >> 9, j = idx & (ND - 1);
  const float* hw = hWhh + (size_t)b * NG;
  float gi = b_ih[j] + b_hh[j] + hw[j];
  float gf = b_ih[j + ND] + b_hh[j + ND] + hw[j + ND];
  float gg = b_ih[j + 2 * ND] + b_hh[j + 2 * ND] + hw[j + 2 * ND];
  float go = b_ih[j + 3 * ND] + b_hh[j + 3 * ND] + hw[j + 3 * ND];
  for (int s = 0; s < KSPL; ++s) {
    const float* Pp = P + ((size_t)s * NB + b) * NG;
    gi += Pp[j]; gf += Pp[j + ND]; gg += Pp[j + 2 * ND]; go += Pp[j + 3 * ND];
  }
  float cn = sigmoidf_(gf) * c[idx] + sigmoidf_(gi) * tanhf(gg);
  float hn = sigmoidf_(go) * tanhf(cn);
  c[idx] = cn;
  h[idx] = hn;
  h_bf[idx] = f2bf(hn);
}

}  // namespace

extern "C" void kernel_launch(void* const* d_in, const int* in_sizes, int n_in,
                              void* d_out, int out_size, void* d_ws, size_t ws_size,
                              hipStream_t stream) {
  (void)in_sizes; (void)n_in; (void)out_size;
  const float* enc    = (const float*)d_in[0];
  const int*   caps   = (const int*)d_in[1];
  const int*   clen   = (const int*)d_in[2];
  const float* W_enc  = (const float*)d_in[3];
  const float* b_enc  = (const float*)d_in[4];
  const float* W_dec  = (const float*)d_in[5];
  const float* b_dec  = (const float*)d_in[6];
  const float* w_att  = (const float*)d_in[7];
  const float* b_att  = (const float*)d_in[8];
  const float* emb    = (const float*)d_in[9];
  const float* W_ih   = (const float*)d_in[10];
  const float* b_ih   = (const float*)d_in[11];
  const float* W_hh   = (const float*)d_in[12];
  const float* b_hh   = (const float*)d_in[13];
  const float* W_h0   = (const float*)d_in[14];
  const float* b_h0   = (const float*)d_in[15];
  const float* W_c0   = (const float*)d_in[16];
  const float* b_c0   = (const float*)d_in[17];
  const float* W_beta = (const float*)d_in[18];
  const float* b_beta = (const float*)d_in[19];
  const float* W_fc   = (const float*)d_in[20];
  const float* b_fc   = (const float*)d_in[21];

  float* ws     = (float*)d_ws;
  float* preds  = (float*)d_out;                   // [B][ML][V]
  float* alphas = preds + (size_t)NB * NML * NV;   // [B][ML][L]

  float* mean_enc = ws + WS_MEAN;
  float* h        = ws + WS_H;
  float* c        = ws + WS_C;
  float* d_buf    = ws + WS_D;
  float* gate     = ws + WS_GATE;
  float* hWhh     = ws + WS_HWHH;
  float* energy   = ws + WS_EN;
  float* PP       = ws + WS_PP;
  short* shb      = (short*)(ws + WS_SHB);
  short* h_bf     = shb + SH_HBF;
  short* xemb     = shb + SH_XEMB;
  short* gctx     = shb + SH_GCTX;
  short* e_proj   = shb + SH_EPROJ;
  short* We_t     = shb + SH_WET;
  short* Wihx_t   = shb + SH_WIHX;
  short* Wall_t   = shb + SH_WALL;
  short* encbf    = shb + SH_ENCBF;
  const bool use_bf = ws_size >= BYTES_ENC;

  // one-time weight transposes (dst[n][k] bf16)
  k_tcvt<<<dim3(NA / 32, NE / 32), dim3(32, 8), 0, stream>>>(W_enc, NE, NA, We_t, NE, 0);
  k_tcvt<<<dim3(NG / 32, KXG / 32), dim3(32, 8), 0, stream>>>(W_ih, KXG, NG, Wihx_t, KXG, 0);
  k_tcvt<<<dim3(NA / 32, ND / 32), dim3(32, 8), 0, stream>>>(W_dec, ND, NA, Wall_t, ND, 0);
  k_tcvt<<<dim3(NE / 32, ND / 32), dim3(32, 8), 0, stream>>>(
      W_beta, ND, NE, Wall_t + (size_t)OFF_GATE * ND, ND, 0);
  k_tcvt<<<dim3(NG / 32, ND / 32), dim3(32, 8), 0, stream>>>(
      W_hh, ND, NG, Wall_t + (size_t)OFF_HWHH * ND, ND, 0);
  k_tcvt<<<dim3((NV + 31) / 32, ND / 32), dim3(32, 8), 0, stream>>>(
      W_fc, ND, NV, Wall_t + (size_t)OFF_PRED * ND, ND, 0);
  if (use_bf)
    k_prep<true><<<dim3(NE / 256, NB), 256, 0, stream>>>(enc, encbf, mean_enc);
  else
    k_prep<false><<<dim3(NE / 256, NB), 256, 0, stream>>>(enc, encbf, mean_enc);
  k_xemb<<<(NML * NB * NM) / 256, 256, 0, stream>>>(caps, emb, xemb);

  k_init0<<<dim3(256, 16), 256, 0, stream>>>(mean_enc, W_h0, W_c0, PP);
  k_init1<<<(NB * ND) / 256, 256, 0, stream>>>(PP, b_h0, b_c0, h, c, h_bf);
  if (use_bf)
    k_eproj<true><<<dim3((NB * NL) / 128, NA / 128), 256, 0, stream>>>(enc, encbf, We_t,
                                                                       b_enc, e_proj);
  else
    k_eproj<false><<<dim3((NB * NL) / 128, NA / 128), 256, 0, stream>>>(enc, encbf, We_t,
                                                                        b_enc, e_proj);
  // h0-dependent projections only (d, gate, hWhh): first 72 column-blocks
  k_hgemm<<<OFF_PRED / 64, 256, 0, stream>>>(h_bf, Wall_t, b_dec, b_beta, b_fc, clen,
                                             d_buf, gate, hWhh, preds, 0);

  for (int t = 0; t < NML; ++t) {
    k_energy<<<(NB * NL) / 4, 256, 0, stream>>>(e_proj, d_buf, w_att, b_att, energy);
    if (use_bf)
      k_ctx<true><<<dim3(NE / 512, NB), 256, 0, stream>>>(encbf, enc, energy, gate, clen,
                                                          gctx, alphas, t);
    else
      k_ctx<false><<<dim3(NE / 512, NB), 256, 0, stream>>>(encbf, enc, energy, gate, clen,
                                                           gctx, alphas, t);
    k_gates<<<dim3(NG / 64, KSPL), 256, 0, stream>>>(xemb + (size_t)t * NB * NM, gctx,
                                                     Wihx_t, PP);
    k_lstm<<<(NB * ND) / 256, 256, 0, stream>>>(PP, hWhh, b_ih, b_hh, h, c, h_bf);
    // fused: preds(t) + d/gate/hWhh for step t+1
    k_hgemm<<<(NALL + 63) / 64, 256, 0, stream>>>(h_bf, Wall_t, b_dec, b_beta, b_fc, clen,
                                                  d_buf, gate, hWhh, preds, t);
  }
}